// Round 1
// baseline (257.900 us; speedup 1.0000x reference)
//
#include <hip/hip_runtime.h>
#include <stdint.h>

typedef unsigned short u16;

#define MTOK 4096
#define CIN  3072
#define COUT 3072
#define RANK 32
#define KT48 48
#define RS   3136       // row stride for xdq/wdq (6272 B: gcd with 4096 = 128 -> good HBM channel spread)
#define LKSPLIT 16
#define LKC (CIN/LKSPLIT)   // 192 = 3 k-tiles

// prep grid: [0, LORA_BLK) fused lora+quant panels, rest wdq rows
#define LORA_BLK (MTOK/128*LKSPLIT)  // 512
#define WDQ_BLK COUT                 // 3072

// Workspace:
//   xdq:     (MTOK, RS) bf16    quantized activations (cols 0..3071 valid)
//   wdq:     (COUT, RS) bf16    dequantized weights
//   pu_bf:   (COUT, RANK) bf16  proj_up cast
//   lora_bf: (MTOK, RANK) bf16  reduced lora activations
//   lp:      (LKSPLIT, MTOK, RANK) f32  lora K-split partials (deterministic)

typedef __attribute__((ext_vector_type(8))) short bf16x8;
typedef __attribute__((ext_vector_type(4))) float f32x4;

__device__ __forceinline__ u16 f2bf(float f) {
  union { float f; unsigned u; } v; v.f = f;
  unsigned r = v.u + 0x7FFFu + ((v.u >> 16) & 1u);  // RNE
  return (u16)(r >> 16);
}

__device__ __forceinline__ void gload_lds16(const void* g, void* l) {
  __builtin_amdgcn_global_load_lds(
      (const __attribute__((address_space(1))) unsigned int*)g,
      (__attribute__((address_space(3))) unsigned int*)l, 16, 0, 0);
}

__device__ __forceinline__ float quant1(float xs, float ascale, float qd) {
  float q = rintf(xs / qd);                      // jnp.round = RNE, exact IEEE div
  q = fminf(fmaxf(q, -8.f), 7.f);
  return q * ascale;
}

// Fused prep: lora-panel blocks (also emit quantized xdq for their chunk — x read ONCE)
// + weight dequant rows.  (unchanged this round — isolate the GEMM change)
__global__ __launch_bounds__(256) void prep_kernel(
    const float* __restrict__ x, const float* __restrict__ smooth,
    const int* __restrict__ qw, const float* __restrict__ wsc,
    const float* __restrict__ pd, const float* __restrict__ pu,
    u16* __restrict__ xdq, u16* __restrict__ wdq, u16* __restrict__ pu_bf,
    float* __restrict__ lp)
{
  const int b = blockIdx.x;
  const int t = threadIdx.x;

  if (b < LORA_BLK) {
    // ---- panel (m0..m0+128) x K-chunk kblk: quantize to xdq + lora partial to lp ----
    __shared__ __align__(16) u16 sA[128 * 64];
    __shared__ __align__(16) u16 sB[32 * 64];
    const int m0 = (b >> 4) * 128;        // 32 m-panels
    const int kblk = b & 15;              // 16 K-splits
    const int wave = t >> 6, lane = t & 63;
    const int lm = lane & 15, lkq = (lane >> 4) * 8;

    f32x4 acc[2][2];
    const f32x4 fz = {0.f, 0.f, 0.f, 0.f};
#pragma unroll
    for (int i = 0; i < 2; ++i)
#pragma unroll
      for (int j = 0; j < 2; ++j) acc[i][j] = fz;

    for (int kt = 0; kt < LKC / 64; ++kt) {
      const int k0 = kblk * LKC + kt * 64;
      const int col = (t & 15) * 4;       // 16 lanes x 4 = one 64-quant-group per row
#pragma unroll
      for (int it = 0; it < 8; ++it) {
        const int row = it * 16 + (t >> 4);
        const float4 xv = *(const float4*)(x + (size_t)(m0 + row) * CIN + k0 + col);
        const float4 sv = *(const float4*)(smooth + k0 + col);
        const float xs0 = xv.x / sv.x, xs1 = xv.y / sv.y;
        const float xs2 = xv.z / sv.z, xs3 = xv.w / sv.w;
        // bf16 xs -> LDS for the lora MFMA
        ushort4 ov;
        ov.x = f2bf(xs0); ov.y = f2bf(xs1); ov.z = f2bf(xs2); ov.w = f2bf(xs3);
        *(ushort4*)&sA[row * 64 + col] = ov;
        // group quant (amax across the 16-lane subgroup) -> xdq
        float a = fmaxf(fmaxf(fabsf(xs0), fabsf(xs1)), fmaxf(fabsf(xs2), fabsf(xs3)));
#pragma unroll
        for (int off = 1; off < 16; off <<= 1) a = fmaxf(a, __shfl_xor(a, off));
        const float ascale = a / 7.0f;
        const float qd = fmaxf(ascale, 1e-8f);
        ushort4 oq;
        oq.x = f2bf(quant1(xs0, ascale, qd));
        oq.y = f2bf(quant1(xs1, ascale, qd));
        oq.z = f2bf(quant1(xs2, ascale, qd));
        oq.w = f2bf(quant1(xs3, ascale, qd));
        *(ushort4*)(xdq + (size_t)(m0 + row) * RS + k0 + col) = oq;
      }
#pragma unroll
      for (int i = 0; i < 8; ++i) {
        const int idx = i * 256 + t;
        const int k = idx >> 5, r = idx & 31;
        sB[r * 64 + k] = f2bf(pd[(size_t)(k0 + k) * RANK + r]);
      }
      __syncthreads();
#pragma unroll
      for (int kk = 0; kk < 2; ++kk) {
        const int ko = kk * 32 + lkq;
        bf16x8 af[2], bfr[2];
#pragma unroll
        for (int i = 0; i < 2; ++i)
          af[i] = *(const bf16x8*)&sA[(wave * 32 + i * 16 + lm) * 64 + ko];
#pragma unroll
        for (int j = 0; j < 2; ++j)
          bfr[j] = *(const bf16x8*)&sB[(j * 16 + lm) * 64 + ko];
#pragma unroll
        for (int i = 0; i < 2; ++i)
#pragma unroll
          for (int j = 0; j < 2; ++j)
            acc[i][j] = __builtin_amdgcn_mfma_f32_16x16x32_bf16(af[i], bfr[j], acc[i][j], 0, 0, 0);
      }
      __syncthreads();
    }
    float* lpk = lp + (size_t)kblk * MTOK * RANK;
#pragma unroll
    for (int i = 0; i < 2; ++i)
#pragma unroll
      for (int j = 0; j < 2; ++j) {
        const int col = j * 16 + lm;
        const int row0 = m0 + wave * 32 + i * 16 + (lane >> 4) * 4;
#pragma unroll
        for (int r = 0; r < 4; ++r)
          lpk[(size_t)(row0 + r) * RANK + col] = acc[i][j][r];
      }
  } else {
    // ---- weight dequant row + pu_bf cast ----
    const int o = b - LORA_BLK;
    const int4* qrow = (const int4*)(qw + (size_t)o * CIN);
    u16* orow = wdq + (size_t)o * RS;
#pragma unroll
    for (int p = 0; p < 3; ++p) {
      const int c4 = p * 256 + t;
      const int g = (c4 * 4) >> 6;
      const float ws = wsc[g * COUT + o];    // wscales is (G, C_out)
      const int4 qv = qrow[c4];
      ushort4 ov;
      ov.x = f2bf((float)(qv.x - 8) * ws);
      ov.y = f2bf((float)(qv.y - 8) * ws);
      ov.z = f2bf((float)(qv.z - 8) * ws);
      ov.w = f2bf((float)(qv.w - 8) * ws);
      ((ushort4*)orow)[c4] = ov;
    }
    if (t < RANK) pu_bf[(size_t)o * RANK + t] = f2bf(pu[(size_t)o * RANK + t]);
  }
}

// Reduce lora K-split partials -> bf16 lora_bf (M, 32).
__global__ __launch_bounds__(256) void lora_fix_kernel(
    const float* __restrict__ lp, u16* __restrict__ lora_bf)
{
  const int idx = blockIdx.x * 256 + threadIdx.x;   // MTOK*RANK
  const int m = idx >> 5, c = idx & 31;
  float s = 0.f;
#pragma unroll
  for (int k = 0; k < LKSPLIT; ++k) s += lp[((size_t)k * MTOK + m) * RANK + c];
  lora_bf[(size_t)m * RANK + c] = f2bf(s);
}

// ---------------------------------------------------------------------------
// Main GEMM: 256x256 tile, 8-wave (2M x 4N), BK=64, 8-phase schedule with
// counted vmcnt (T3+T4), LDS slot-swizzle (T2), setprio around MFMA (T5).
//
// LDS: A = [2 buf][2 half][128 rows][64 cols] bf16 (64 KiB)
//      B = same (64 KiB)  -> 128 KiB total.
// Per wave: 128 rows (mh in {0,1} selects A-half; rows mh*128+wm*64+i*16+lm)
//           x 64 cols (nh selects B-half; cols nh*128+wn*32+j*16+lm).
// Each phase computes ONE (mh,nh) quadrant = 16 MFMA, so a phase touches
// exactly one A-half and one B-half -> half-tile granular pipelining works.
//
// Staging schedule during tile T (one half-tile per phase):
//   P0: A1 of T+1   P1: B0 of T+1   P2: A0 of T+2   P3: B1 of T+2
// Slot-reuse safety: a slot's last ds_read is ISSUED in the phase listed
// below and completed by that phase's lgkmcnt(0); the overwriting stage for
// the same slot (2 tiles later) is issued >= 2 phases after:
//   A0 reads issued P0 (reused from regs P1)  / overwritten at P2 two tiles on
//   B0 reads issued P0 (reused P3)            / overwritten at P1
//   B1 reads issued P1 (reused P2)            / overwritten at P3
//   A1 reads issued P2 (reused P3)            / overwritten at P0
// Boundary s_waitcnt vmcnt(4) forces all of tile T+1's four halves while
// leaving tile T+2's first two half-tiles (4 loads) in flight — never 0.
//
// LDS swizzle (both-sides-or-neither, rule #21): within a 128-row half,
// 16B slot s of row r holds global col-chunk c16 where
//   s = ((c16&3)<<1 | (c16>>2)) ^ ((r>>2)&7)        (involution pair below)
// A frag read (fixed kk) then touches slots {0..7} with exactly 8 lanes per
// 16B slot -> minimal LDS bank aliasing for ds_read_b128.
// ---------------------------------------------------------------------------

__device__ __forceinline__ void stage_half(const u16* __restrict__ g, u16* lds_base,
                                           int kt, int half, int buf, int t) {
#pragma unroll
  for (int r = 0; r < 2; ++r) {
    const int ld = r * 512 + t;           // 16B-chunk id 0..1023 (8 chunks/row)
    const int row = ld >> 3;              // 0..127 within half
    const int d = ld & 7;                 // dest slot
    const int s0 = d ^ ((row >> 2) & 7);
    const int c16 = ((s0 & 1) << 2) | (s0 >> 1);   // source col-chunk
    gload_lds16(g + (size_t)(half * 128 + row) * RS + kt * 64 + c16 * 8,
                lds_base + buf * 16384 + half * 8192 + ld * 8);
  }
}

#define DSA(buf, mh) \
  _Pragma("unroll") for (int i = 0; i < 4; ++i) { \
    const int rl = wm * 64 + i * 16 + lm; \
    _Pragma("unroll") for (int kk = 0; kk < 2; ++kk) \
      af[i][kk] = *(const bf16x8*)&lds[(buf)*16384 + (mh)*8192 + rl * 64 + \
                    ((((q4 << 1) | kk) ^ ((rl >> 2) & 7)) << 3)]; \
  }

#define DSB(buf, nh, BF) \
  _Pragma("unroll") for (int j = 0; j < 2; ++j) { \
    const int rl = wn * 32 + j * 16 + lm; \
    _Pragma("unroll") for (int kk = 0; kk < 2; ++kk) \
      BF[j][kk] = *(const bf16x8*)&lds[32768 + (buf)*16384 + (nh)*8192 + rl * 64 + \
                    ((((q4 << 1) | kk) ^ ((rl >> 2) & 7)) << 3)]; \
  }

#define MFMA_Q(mh, nh, BF) \
  __builtin_amdgcn_s_setprio(1); \
  _Pragma("unroll") for (int i = 0; i < 4; ++i) \
  _Pragma("unroll") for (int j = 0; j < 2; ++j) \
  _Pragma("unroll") for (int kk = 0; kk < 2; ++kk) \
    acc[(mh)*4 + i][(nh)*2 + j] = __builtin_amdgcn_mfma_f32_16x16x32_bf16( \
        af[i][kk], BF[j][kk], acc[(mh)*4 + i][(nh)*2 + j], 0, 0, 0); \
  __builtin_amdgcn_s_setprio(0);

#define PH_OPEN() \
  __builtin_amdgcn_sched_barrier(0); \
  __builtin_amdgcn_s_barrier(); \
  asm volatile("s_waitcnt lgkmcnt(0)" ::: "memory"); \
  __builtin_amdgcn_sched_barrier(0)

#define PH_CLOSE() \
  __builtin_amdgcn_sched_barrier(0); \
  __builtin_amdgcn_s_barrier(); \
  __builtin_amdgcn_sched_barrier(0)

#define VM4() asm volatile("s_waitcnt vmcnt(4)" ::: "memory")
#define VM0() asm volatile("s_waitcnt vmcnt(0)" ::: "memory")

// One K-tile (4 phases). S0..S3 = stage statements, VMI = boundary vmcnt.
#define TILE8(cur, S0, S1, S2, S3, VMI) do { \
  DSA(cur, 0); DSB(cur, 0, bf0); S0; \
  PH_OPEN(); MFMA_Q(0, 0, bf0); PH_CLOSE(); \
  DSB(cur, 1, bf1); S1; \
  PH_OPEN(); MFMA_Q(0, 1, bf1); PH_CLOSE(); \
  DSA(cur, 1); S2; \
  PH_OPEN(); MFMA_Q(1, 1, bf1); PH_CLOSE(); \
  S3; \
  PH_OPEN(); MFMA_Q(1, 0, bf0); VMI; PH_CLOSE(); \
} while (0)

__global__ __launch_bounds__(512, 2) void gemm_kernel(
    const u16* __restrict__ xdq, const u16* __restrict__ wdq,
    const u16* __restrict__ pu_bf, const u16* __restrict__ lora_bf,
    const float* __restrict__ bias, float* __restrict__ out)
{
  __shared__ __align__(16) u16 lds[65536];   // 128 KiB: A[0..32767], B[32768..]

  const int t = threadIdx.x;
  const int wid = t >> 6, lane = t & 63;
  const int wm = wid >> 2, wn = wid & 3;     // 2M x 4N wave grid
  const int lm = lane & 15, q4 = lane >> 4;

  // XCD-aware swizzle (192 = 8 XCDs * 24): each XCD gets 2 full M-rows of tiles
  const int wg = blockIdx.x;
  const int swz = (wg & 7) * 24 + (wg >> 3);
  const int by = swz / 12, bx = swz % 12;    // by: M-tile 0..15, bx: N-tile 0..11
  const int m0 = by * 256, n0 = bx * 256;

  const u16* Ag = xdq + (size_t)m0 * RS;
  const u16* Bg = wdq + (size_t)n0 * RS;
  u16* ldsB = lds + 32768;

  f32x4 acc[8][4];
  const f32x4 fz = {0.f, 0.f, 0.f, 0.f};
#pragma unroll
  for (int i = 0; i < 8; ++i)
#pragma unroll
    for (int j = 0; j < 4; ++j) acc[i][j] = fz;

  bf16x8 af[4][2], bf0[2][2], bf1[2][2];

  // Prologue: T0 {A0,B0,A1,B1}, T1 {A0,B1}; force T0, leave T1's 2 ht in flight
  stage_half(Ag, lds,  0, 0, 0, t);
  stage_half(Bg, ldsB, 0, 0, 0, t);
  stage_half(Ag, lds,  0, 1, 0, t);
  stage_half(Bg, ldsB, 0, 1, 0, t);
  stage_half(Ag, lds,  1, 0, 1, t);
  stage_half(Bg, ldsB, 1, 1, 1, t);
  VM4();
  __builtin_amdgcn_s_barrier();
  __builtin_amdgcn_sched_barrier(0);

  // Main loop: tiles 0..45 (two per iteration; buffers parity-static)
  for (int T = 0; T < 46; T += 2) {
    TILE8(0,
          stage_half(Ag, lds,  T + 1, 1, 1, t),
          stage_half(Bg, ldsB, T + 1, 0, 1, t),
          stage_half(Ag, lds,  T + 2, 0, 0, t),
          stage_half(Bg, ldsB, T + 2, 1, 0, t),
          VM4());
    TILE8(1,
          stage_half(Ag, lds,  T + 2, 1, 0, t),
          stage_half(Bg, ldsB, T + 2, 0, 0, t),
          stage_half(Ag, lds,  T + 3, 0, 1, t),
          stage_half(Bg, ldsB, T + 3, 1, 1, t),
          VM4());
  }
  // Epilogue: tile 46 (stage rest of 47, drain), tile 47 (no stages)
  TILE8(0,
        stage_half(Ag, lds,  47, 1, 1, t),
        stage_half(Bg, ldsB, 47, 0, 1, t),
        (void)0,
        (void)0,
        VM0());
  TILE8(1, (void)0, (void)0, (void)0, (void)0, (void)0);

  // ---- lora epilogue: acc += lora_act(256x32) . proj_up(256x32)^T (L2-hot) ----
  bf16x8 bl[4];
#pragma unroll
  for (int b = 0; b < 4; ++b) {
    const int bcol = n0 + (b >> 1) * 128 + wn * 32 + (b & 1) * 16 + lm;
    bl[b] = *(const bf16x8*)(pu_bf + (size_t)bcol * RANK + q4 * 8);
  }
#pragma unroll
  for (int a = 0; a < 8; ++a) {
    const int arow = m0 + (a >> 2) * 128 + wm * 64 + (a & 3) * 16 + lm;
    const bf16x8 al = *(const bf16x8*)(lora_bf + (size_t)arow * RANK + q4 * 8);
#pragma unroll
    for (int b = 0; b < 4; ++b)
      acc[a][b] = __builtin_amdgcn_mfma_f32_16x16x32_bf16(al, bl[b], acc[a][b], 0, 0, 0);
  }

  // store: C/D layout col=lane&15, row=(lane>>4)*4+reg  [m89-verified]
#pragma unroll
  for (int b = 0; b < 4; ++b) {
    const int col = n0 + (b >> 1) * 128 + wn * 32 + (b & 1) * 16 + lm;
    const float bv = bias[col];
#pragma unroll
    for (int a = 0; a < 8; ++a) {
      const int row0 = m0 + (a >> 2) * 128 + wm * 64 + (a & 3) * 16 + q4 * 4;
#pragma unroll
      for (int r = 0; r < 4; ++r)
        out[(size_t)(row0 + r) * COUT + col] = acc[a][b][r] + bv;
    }
  }
}

extern "C" void kernel_launch(void* const* d_in, const int* in_sizes, int n_in,
                              void* d_out, int out_size, void* d_ws, size_t ws_size,
                              hipStream_t stream) {
  const float* x      = (const float*)d_in[0];
  const int*   qw     = (const int*)d_in[1];
  const float* wsc    = (const float*)d_in[2];
  const float* smooth = (const float*)d_in[3];
  const float* pd     = (const float*)d_in[4];
  const float* pu     = (const float*)d_in[5];
  const float* bias   = (const float*)d_in[6];
  float* out = (float*)d_out;

  u16* xdq     = (u16*)d_ws;                               // 4096*3136*2 = 25.7 MB
  u16* wdq     = xdq + (size_t)MTOK * RS;                  // 3072*3136*2 = 19.3 MB
  u16* pu_bf   = wdq + (size_t)COUT * RS;                  // 3072*32*2   = 0.2 MB
  u16* lora_bf = pu_bf + (size_t)COUT * RANK;              // 4096*32*2   = 0.3 MB
  float* lp    = (float*)(lora_bf + (size_t)MTOK * RANK);  // 16*4096*32*4 = 8.4 MB

  prep_kernel<<<LORA_BLK + WDQ_BLK, 256, 0, stream>>>(
      x, smooth, qw, wsc, pd, pu, xdq, wdq, pu_bf, lp);
  lora_fix_kernel<<<MTOK * RANK / 256, 256, 0, stream>>>(lp, lora_bf);
  gemm_kernel<<<192, 512, 0, stream>>>(
      xdq, wdq, pu_bf, lora_bf, bias, out);
}

// Round 2
// 226.718 us; speedup vs baseline: 1.1375x; 1.1375x over previous
//
#include <hip/hip_runtime.h>
#include <stdint.h>

typedef unsigned short u16;

#define MTOK 4096
#define CIN  3072
#define COUT 3072
#define RANK 32
#define KT48 48
#define RS   3136       // row stride for xdq/wdq (6272 B: gcd with 4096 = 128 -> good HBM channel spread)
#define LKSPLIT 16
#define LKC (CIN/LKSPLIT)   // 192 = 3 k-tiles

// prep grid: [0, LORA_BLK) fused lora+quant panels, rest wdq rows
#define LORA_BLK (MTOK/128*LKSPLIT)  // 512
#define WDQ_BLK COUT                 // 3072

// Workspace:
//   xdq:     (MTOK, RS) bf16    quantized activations (cols 0..3071 valid)
//   wdq:     (COUT, RS) bf16    dequantized weights
//   pu_bf:   (COUT, RANK) bf16  proj_up cast
//   lora_bf: (MTOK, RANK) bf16  reduced lora activations
//   lp:      (LKSPLIT, MTOK, RANK) f32  lora K-split partials (deterministic)

typedef __attribute__((ext_vector_type(8))) short bf16x8;
typedef __attribute__((ext_vector_type(4))) float f32x4;

__device__ __forceinline__ u16 f2bf(float f) {
  union { float f; unsigned u; } v; v.f = f;
  unsigned r = v.u + 0x7FFFu + ((v.u >> 16) & 1u);  // RNE
  return (u16)(r >> 16);
}

__device__ __forceinline__ void gload_lds16(const void* g, void* l) {
  __builtin_amdgcn_global_load_lds(
      (const __attribute__((address_space(1))) unsigned int*)g,
      (__attribute__((address_space(3))) unsigned int*)l, 16, 0, 0);
}

__device__ __forceinline__ float quant1(float xs, float ascale, float qd) {
  float q = rintf(xs / qd);                      // jnp.round = RNE, exact IEEE div
  q = fminf(fmaxf(q, -8.f), 7.f);
  return q * ascale;
}

// Fused prep: lora-panel blocks (also emit quantized xdq for their chunk — x read ONCE)
// + weight dequant rows.  (unchanged — isolate the GEMM swizzle fix)
__global__ __launch_bounds__(256) void prep_kernel(
    const float* __restrict__ x, const float* __restrict__ smooth,
    const int* __restrict__ qw, const float* __restrict__ wsc,
    const float* __restrict__ pd, const float* __restrict__ pu,
    u16* __restrict__ xdq, u16* __restrict__ wdq, u16* __restrict__ pu_bf,
    float* __restrict__ lp)
{
  const int b = blockIdx.x;
  const int t = threadIdx.x;

  if (b < LORA_BLK) {
    // ---- panel (m0..m0+128) x K-chunk kblk: quantize to xdq + lora partial to lp ----
    __shared__ __align__(16) u16 sA[128 * 64];
    __shared__ __align__(16) u16 sB[32 * 64];
    const int m0 = (b >> 4) * 128;        // 32 m-panels
    const int kblk = b & 15;              // 16 K-splits
    const int wave = t >> 6, lane = t & 63;
    const int lm = lane & 15, lkq = (lane >> 4) * 8;

    f32x4 acc[2][2];
    const f32x4 fz = {0.f, 0.f, 0.f, 0.f};
#pragma unroll
    for (int i = 0; i < 2; ++i)
#pragma unroll
      for (int j = 0; j < 2; ++j) acc[i][j] = fz;

    for (int kt = 0; kt < LKC / 64; ++kt) {
      const int k0 = kblk * LKC + kt * 64;
      const int col = (t & 15) * 4;       // 16 lanes x 4 = one 64-quant-group per row
#pragma unroll
      for (int it = 0; it < 8; ++it) {
        const int row = it * 16 + (t >> 4);
        const float4 xv = *(const float4*)(x + (size_t)(m0 + row) * CIN + k0 + col);
        const float4 sv = *(const float4*)(smooth + k0 + col);
        const float xs0 = xv.x / sv.x, xs1 = xv.y / sv.y;
        const float xs2 = xv.z / sv.z, xs3 = xv.w / sv.w;
        // bf16 xs -> LDS for the lora MFMA
        ushort4 ov;
        ov.x = f2bf(xs0); ov.y = f2bf(xs1); ov.z = f2bf(xs2); ov.w = f2bf(xs3);
        *(ushort4*)&sA[row * 64 + col] = ov;
        // group quant (amax across the 16-lane subgroup) -> xdq
        float a = fmaxf(fmaxf(fabsf(xs0), fabsf(xs1)), fmaxf(fabsf(xs2), fabsf(xs3)));
#pragma unroll
        for (int off = 1; off < 16; off <<= 1) a = fmaxf(a, __shfl_xor(a, off));
        const float ascale = a / 7.0f;
        const float qd = fmaxf(ascale, 1e-8f);
        ushort4 oq;
        oq.x = f2bf(quant1(xs0, ascale, qd));
        oq.y = f2bf(quant1(xs1, ascale, qd));
        oq.z = f2bf(quant1(xs2, ascale, qd));
        oq.w = f2bf(quant1(xs3, ascale, qd));
        *(ushort4*)(xdq + (size_t)(m0 + row) * RS + k0 + col) = oq;
      }
#pragma unroll
      for (int i = 0; i < 8; ++i) {
        const int idx = i * 256 + t;
        const int k = idx >> 5, r = idx & 31;
        sB[r * 64 + k] = f2bf(pd[(size_t)(k0 + k) * RANK + r]);
      }
      __syncthreads();
#pragma unroll
      for (int kk = 0; kk < 2; ++kk) {
        const int ko = kk * 32 + lkq;
        bf16x8 af[2], bfr[2];
#pragma unroll
        for (int i = 0; i < 2; ++i)
          af[i] = *(const bf16x8*)&sA[(wave * 32 + i * 16 + lm) * 64 + ko];
#pragma unroll
        for (int j = 0; j < 2; ++j)
          bfr[j] = *(const bf16x8*)&sB[(j * 16 + lm) * 64 + ko];
#pragma unroll
        for (int i = 0; i < 2; ++i)
#pragma unroll
          for (int j = 0; j < 2; ++j)
            acc[i][j] = __builtin_amdgcn_mfma_f32_16x16x32_bf16(af[i], bfr[j], acc[i][j], 0, 0, 0);
      }
      __syncthreads();
    }
    float* lpk = lp + (size_t)kblk * MTOK * RANK;
#pragma unroll
    for (int i = 0; i < 2; ++i)
#pragma unroll
      for (int j = 0; j < 2; ++j) {
        const int col = j * 16 + lm;
        const int row0 = m0 + wave * 32 + i * 16 + (lane >> 4) * 4;
#pragma unroll
        for (int r = 0; r < 4; ++r)
          lpk[(size_t)(row0 + r) * RANK + col] = acc[i][j][r];
      }
  } else {
    // ---- weight dequant row + pu_bf cast ----
    const int o = b - LORA_BLK;
    const int4* qrow = (const int4*)(qw + (size_t)o * CIN);
    u16* orow = wdq + (size_t)o * RS;
#pragma unroll
    for (int p = 0; p < 3; ++p) {
      const int c4 = p * 256 + t;
      const int g = (c4 * 4) >> 6;
      const float ws = wsc[g * COUT + o];    // wscales is (G, C_out)
      const int4 qv = qrow[c4];
      ushort4 ov;
      ov.x = f2bf((float)(qv.x - 8) * ws);
      ov.y = f2bf((float)(qv.y - 8) * ws);
      ov.z = f2bf((float)(qv.z - 8) * ws);
      ov.w = f2bf((float)(qv.w - 8) * ws);
      ((ushort4*)orow)[c4] = ov;
    }
    if (t < RANK) pu_bf[(size_t)o * RANK + t] = f2bf(pu[(size_t)o * RANK + t]);
  }
}

// Reduce lora K-split partials -> bf16 lora_bf (M, 32).
__global__ __launch_bounds__(256) void lora_fix_kernel(
    const float* __restrict__ lp, u16* __restrict__ lora_bf)
{
  const int idx = blockIdx.x * 256 + threadIdx.x;   // MTOK*RANK
  const int m = idx >> 5, c = idx & 31;
  float s = 0.f;
#pragma unroll
  for (int k = 0; k < LKSPLIT; ++k) s += lp[((size_t)k * MTOK + m) * RANK + c];
  lora_bf[(size_t)m * RANK + c] = f2bf(s);
}

// ---------------------------------------------------------------------------
// Main GEMM: 256x256 tile, 8-wave (2M x 4N), BK=64, 8-phase schedule with
// counted vmcnt (T3+T4), LDS slot-swizzle (T2), setprio around MFMA (T5).
//
// LDS: A = [2 buf][2 half][128 rows][64 cols] bf16 (64 KiB), B same -> 128 KiB.
//
// R1 post-mortem fix: 64-col bf16 rows are 128 B = one full 32-bank wrap, so
// the bank group of a ds_read_b128 depends ONLY on the 16B slot index.
// Conflict-free requires the slot XOR mask to span all 8 values within each
// 16-lane group -> must use (row & 7) (= lm&7, full 3 bits), NOT (row>>2)&7
// (only 2 bits of lm -> 4 slots x 4 lanes = 4-way conflict, 2.1e7 measured).
// Swizzle (rule #21, both-sides): slot s of row r holds global col-chunk
//   c16 = s ^ (r & 7)   (involution; applied at stage source AND at read)
// Read for (kk,q4): slot = (kk*4 + q4) ^ (rl & 7) -> within each 16-lane
// group: 8 distinct slots x 2 lanes = 2-way = free (m136).
//
// Staging schedule during tile T (one half-tile per phase):
//   P0: A1 of T+1   P1: B0 of T+1   P2: A0 of T+2   P3: B1 of T+2
// Slot-reuse ledger (read-issue phase vs overwrite phase, 2 tiles apart):
//   A0 read P0 / overwritten P2 ; B0 read P0 (reused P3) / overwritten P1
//   B1 read P1 (reused P2) / overwritten P3 ; A1 read P2 (reused P3) / ovw P0
// Boundary s_waitcnt vmcnt(4): forces tile T+1's four halves complete while
// leaving tile T+2's two staged half-tiles (4 loads/thread) in flight.
// ---------------------------------------------------------------------------

__device__ __forceinline__ void stage_half(const u16* __restrict__ g, u16* lds_base,
                                           int kt, int half, int buf, int t) {
#pragma unroll
  for (int r = 0; r < 2; ++r) {
    const int ld = r * 512 + t;           // 16B-chunk id 0..1023 (8 chunks/row)
    const int row = ld >> 3;              // 0..127 within half
    const int d = ld & 7;                 // dest slot
    const int c16 = d ^ (row & 7);        // source col-chunk (involution)
    gload_lds16(g + (size_t)(half * 128 + row) * RS + kt * 64 + c16 * 8,
                lds_base + buf * 16384 + half * 8192 + ld * 8);
  }
}

#define DSA(buf, mh) \
  _Pragma("unroll") for (int i = 0; i < 4; ++i) { \
    const int rl = wm * 64 + i * 16 + lm; \
    _Pragma("unroll") for (int kk = 0; kk < 2; ++kk) \
      af[i][kk] = *(const bf16x8*)&lds[(buf)*16384 + (mh)*8192 + rl * 64 + \
                    ((((kk << 2) | q4) ^ (rl & 7)) << 3)]; \
  }

#define DSB(buf, nh, BF) \
  _Pragma("unroll") for (int j = 0; j < 2; ++j) { \
    const int rl = wn * 32 + j * 16 + lm; \
    _Pragma("unroll") for (int kk = 0; kk < 2; ++kk) \
      BF[j][kk] = *(const bf16x8*)&lds[32768 + (buf)*16384 + (nh)*8192 + rl * 64 + \
                    ((((kk << 2) | q4) ^ (rl & 7)) << 3)]; \
  }

#define MFMA_Q(mh, nh, BF) \
  __builtin_amdgcn_s_setprio(1); \
  _Pragma("unroll") for (int i = 0; i < 4; ++i) \
  _Pragma("unroll") for (int j = 0; j < 2; ++j) \
  _Pragma("unroll") for (int kk = 0; kk < 2; ++kk) \
    acc[(mh)*4 + i][(nh)*2 + j] = __builtin_amdgcn_mfma_f32_16x16x32_bf16( \
        af[i][kk], BF[j][kk], acc[(mh)*4 + i][(nh)*2 + j], 0, 0, 0); \
  __builtin_amdgcn_s_setprio(0);

#define PH_OPEN() \
  __builtin_amdgcn_sched_barrier(0); \
  __builtin_amdgcn_s_barrier(); \
  asm volatile("s_waitcnt lgkmcnt(0)" ::: "memory"); \
  __builtin_amdgcn_sched_barrier(0)

#define PH_CLOSE() \
  __builtin_amdgcn_sched_barrier(0); \
  __builtin_amdgcn_s_barrier(); \
  __builtin_amdgcn_sched_barrier(0)

#define VM4() asm volatile("s_waitcnt vmcnt(4)" ::: "memory")
#define VM0() asm volatile("s_waitcnt vmcnt(0)" ::: "memory")

// One K-tile (4 phases). S0..S3 = stage statements, VMI = boundary vmcnt.
#define TILE8(cur, S0, S1, S2, S3, VMI) do { \
  DSA(cur, 0); DSB(cur, 0, bf0); S0; \
  PH_OPEN(); MFMA_Q(0, 0, bf0); PH_CLOSE(); \
  DSB(cur, 1, bf1); S1; \
  PH_OPEN(); MFMA_Q(0, 1, bf1); PH_CLOSE(); \
  DSA(cur, 1); S2; \
  PH_OPEN(); MFMA_Q(1, 1, bf1); PH_CLOSE(); \
  S3; \
  PH_OPEN(); MFMA_Q(1, 0, bf0); VMI; PH_CLOSE(); \
} while (0)

__global__ __launch_bounds__(512, 2) void gemm_kernel(
    const u16* __restrict__ xdq, const u16* __restrict__ wdq,
    const u16* __restrict__ pu_bf, const u16* __restrict__ lora_bf,
    const float* __restrict__ bias, float* __restrict__ out)
{
  __shared__ __align__(16) u16 lds[65536];   // 128 KiB: A[0..32767], B[32768..]

  const int t = threadIdx.x;
  const int wid = t >> 6, lane = t & 63;
  const int wm = wid >> 2, wn = wid & 3;     // 2M x 4N wave grid
  const int lm = lane & 15, q4 = lane >> 4;

  // XCD-aware swizzle (192 = 8 XCDs * 24): each XCD gets 2 full M-rows of tiles
  const int wg = blockIdx.x;
  const int swz = (wg & 7) * 24 + (wg >> 3);
  const int by = swz / 12, bx = swz % 12;    // by: M-tile 0..15, bx: N-tile 0..11
  const int m0 = by * 256, n0 = bx * 256;

  const u16* Ag = xdq + (size_t)m0 * RS;
  const u16* Bg = wdq + (size_t)n0 * RS;
  u16* ldsB = lds + 32768;

  f32x4 acc[8][4];
  const f32x4 fz = {0.f, 0.f, 0.f, 0.f};
#pragma unroll
  for (int i = 0; i < 8; ++i)
#pragma unroll
    for (int j = 0; j < 4; ++j) acc[i][j] = fz;

  bf16x8 af[4][2], bf0[2][2], bf1[2][2];

  // Prologue: T0 {A0,B0,A1,B1}, T1 {A0,B1}; force T0, leave T1's 2 ht in flight
  stage_half(Ag, lds,  0, 0, 0, t);
  stage_half(Bg, ldsB, 0, 0, 0, t);
  stage_half(Ag, lds,  0, 1, 0, t);
  stage_half(Bg, ldsB, 0, 1, 0, t);
  stage_half(Ag, lds,  1, 0, 1, t);
  stage_half(Bg, ldsB, 1, 1, 1, t);
  VM4();
  __builtin_amdgcn_s_barrier();
  __builtin_amdgcn_sched_barrier(0);

  // Main loop: tiles 0..45 (two per iteration; buffers parity-static)
  for (int T = 0; T < 46; T += 2) {
    TILE8(0,
          stage_half(Ag, lds,  T + 1, 1, 1, t),
          stage_half(Bg, ldsB, T + 1, 0, 1, t),
          stage_half(Ag, lds,  T + 2, 0, 0, t),
          stage_half(Bg, ldsB, T + 2, 1, 0, t),
          VM4());
    TILE8(1,
          stage_half(Ag, lds,  T + 2, 1, 0, t),
          stage_half(Bg, ldsB, T + 2, 0, 0, t),
          stage_half(Ag, lds,  T + 3, 0, 1, t),
          stage_half(Bg, ldsB, T + 3, 1, 1, t),
          VM4());
  }
  // Epilogue: tile 46 (stage rest of 47, drain), tile 47 (no stages)
  TILE8(0,
        stage_half(Ag, lds,  47, 1, 1, t),
        stage_half(Bg, ldsB, 47, 0, 1, t),
        (void)0,
        (void)0,
        VM0());
  TILE8(1, (void)0, (void)0, (void)0, (void)0, (void)0);

  // ---- lora epilogue: acc += lora_act(256x32) . proj_up(256x32)^T (L2-hot) ----
  bf16x8 bl[4];
#pragma unroll
  for (int b = 0; b < 4; ++b) {
    const int bcol = n0 + (b >> 1) * 128 + wn * 32 + (b & 1) * 16 + lm;
    bl[b] = *(const bf16x8*)(pu_bf + (size_t)bcol * RANK + q4 * 8);
  }
#pragma unroll
  for (int a = 0; a < 8; ++a) {
    const int arow = m0 + (a >> 2) * 128 + wm * 64 + (a & 3) * 16 + lm;
    const bf16x8 al = *(const bf16x8*)(lora_bf + (size_t)arow * RANK + q4 * 8);
#pragma unroll
    for (int b = 0; b < 4; ++b)
      acc[a][b] = __builtin_amdgcn_mfma_f32_16x16x32_bf16(al, bl[b], acc[a][b], 0, 0, 0);
  }

  // store: C/D layout col=lane&15, row=(lane>>4)*4+reg  [m89-verified]
#pragma unroll
  for (int b = 0; b < 4; ++b) {
    const int col = n0 + (b >> 1) * 128 + wn * 32 + (b & 1) * 16 + lm;
    const float bv = bias[col];
#pragma unroll
    for (int a = 0; a < 8; ++a) {
      const int row0 = m0 + (a >> 2) * 128 + wm * 64 + (a & 3) * 16 + q4 * 4;
#pragma unroll
      for (int r = 0; r < 4; ++r)
        out[(size_t)(row0 + r) * COUT + col] = acc[a][b][r] + bv;
    }
  }
}

extern "C" void kernel_launch(void* const* d_in, const int* in_sizes, int n_in,
                              void* d_out, int out_size, void* d_ws, size_t ws_size,
                              hipStream_t stream) {
  const float* x      = (const float*)d_in[0];
  const int*   qw     = (const int*)d_in[1];
  const float* wsc    = (const float*)d_in[2];
  const float* smooth = (const float*)d_in[3];
  const float* pd     = (const float*)d_in[4];
  const float* pu     = (const float*)d_in[5];
  const float* bias   = (const float*)d_in[6];
  float* out = (float*)d_out;

  u16* xdq     = (u16*)d_ws;                               // 4096*3136*2 = 25.7 MB
  u16* wdq     = xdq + (size_t)MTOK * RS;                  // 3072*3136*2 = 19.3 MB
  u16* pu_bf   = wdq + (size_t)COUT * RS;                  // 3072*32*2   = 0.2 MB
  u16* lora_bf = pu_bf + (size_t)COUT * RANK;              // 4096*32*2   = 0.3 MB
  float* lp    = (float*)(lora_bf + (size_t)MTOK * RANK);  // 16*4096*32*4 = 8.4 MB

  prep_kernel<<<LORA_BLK + WDQ_BLK, 256, 0, stream>>>(
      x, smooth, qw, wsc, pd, pu, xdq, wdq, pu_bf, lp);
  lora_fix_kernel<<<MTOK * RANK / 256, 256, 0, stream>>>(lp, lora_bf);
  gemm_kernel<<<192, 512, 0, stream>>>(
      xdq, wdq, pu_bf, lora_bf, bias, out);
}